// Round 1
// baseline (124.304 us; speedup 1.0000x reference)
//
#include <hip/hip_runtime.h>
#include <hip/hip_bf16.h>
#include <math.h>

// VariableSelectionNetwork — MI355X (gfx950), round 11
//
// Identity: scorer LayerNorm over a size-1 axis => output == sc_ln_b, so
// softmax weights W[f] = softmax(sc_ln_b) are constant and the scorer GRN is
// dead code. Remaining: mix = x @ WT^T + c ; post-GRN (3x 256x256) ; gated
// skip ; LayerNorm(256).
//
// Round 11: SINGLE fused kernel, no workspace, no prep launch.
//   Evidence: timed region is dominated by harness 256 MiB ws re-poison
//   fills (~42 us each, top-5 dispatches); our kernels are <41 us combined.
//   Largest controllable term = second launch + prep work. So:
//   - WT/c computed per block into LDS (coalesced 64 KB L2 read, ~0.5 us)
//   - FC1/FC2/GATE fragments loaded as fp32 direct from row-major weights
//     (2x float4 per lane, 128 B/row contiguous) + in-register cvt to bf16.
//     Weights (832 KB fp32) stay L2-resident per XCD.
//   GEMM structure itself is the round-5 main (best measured), unchanged.

typedef __bf16 bf16;
typedef __bf16 bf16x8 __attribute__((ext_vector_type(8)));
typedef __bf16 bf16x4 __attribute__((ext_vector_type(4)));
typedef float f32x4 __attribute__((ext_vector_type(4)));

#define NTOK 8192
#define D_   256
#define F_   32

static __device__ inline bf16x8 cvt8(float4 a, float4 b) {
  bf16x8 v = {(bf16)a.x, (bf16)a.y, (bf16)a.z, (bf16)a.w,
              (bf16)b.x, (bf16)b.y, (bf16)b.z, (bf16)b.w};
  return v;
}

// ---- fused: 32 tokens / 4-wave block; wave w owns cols [64w, 64w+64) ----
__global__ __launch_bounds__(256, 1) void vsn_fused(
    const float* __restrict__ x,
    const float* __restrict__ proj_w, const float* __restrict__ proj_b,
    const float* __restrict__ sc_ln_b,
    const float* __restrict__ FC1, const float* __restrict__ fc1_b,
    const float* __restrict__ FC2, const float* __restrict__ fc2_b,
    const float* __restrict__ GATE, const float* __restrict__ gate_b,
    const float* __restrict__ ln_g, const float* __restrict__ ln_b,
    float* __restrict__ out)
{
  __shared__ __align__(16) bf16  sWT[256][40];   // padded row: 80 B (16B mult)
  __shared__ float sC[256];
  __shared__ __align__(16) bf16  sAct[2][32][264]; // ping-pong bf16 acts (A op)
  __shared__ __align__(16) float sY[32][260];      // fp32 y2 for LayerNorm

  const int tid  = threadIdx.x;
  const int w    = tid >> 6;
  const int lane = tid & 63;
  const int lm   = lane & 15;
  const int lq   = lane >> 4;
  const int j0   = w * 4;
  const int tok0 = blockIdx.x * 32;

  // ---- prologue (was vsn_prep block 48): softmax(sc_ln_b) -> WT, c ----
  {
    float wv[F_];
    float mx = -3.0e38f;
    #pragma unroll
    for (int f = 0; f < F_; f++) { wv[f] = sc_ln_b[f]; mx = fmaxf(mx, wv[f]); }
    float se = 0.0f;
    #pragma unroll
    for (int f = 0; f < F_; f++) { wv[f] = __expf(wv[f] - mx); se += wv[f]; }
    const float inv = 1.0f / se;

    const int d = tid;                       // each thread owns one column d
    float acc = 0.0f;
    #pragma unroll
    for (int q = 0; q < 4; q++) {
      bf16x8 v;
      #pragma unroll
      for (int e = 0; e < 8; e++) {
        int f = q * 8 + e;
        float wf = wv[f] * inv;
        acc += wf * proj_b[f * D_ + d];      // coalesced across threads
        v[e] = (bf16)(wf * proj_w[f * D_ + d]);
      }
      *(bf16x8*)(&sWT[d][q * 8]) = v;
    }
    sC[d] = acc;
  }
  __syncthreads();

  // ---- phase 1: mix = x @ WT^T + c (K=32); 2 M-tiles share each B ----
  bf16x4 mixh[2][4];
  {
    bf16x8 a[2];
    #pragma unroll
    for (int t = 0; t < 2; t++) {
      const float* xp = x + (size_t)(tok0 + t * 16 + lm) * F_ + lq * 8;
      float4 x0 = *(const float4*)xp;
      float4 x1 = *(const float4*)(xp + 4);
      a[t] = cvt8(x0, x1);
    }
    #pragma unroll
    for (int jj = 0; jj < 4; jj++) {
      int n = (j0 + jj) * 16 + lm;
      bf16x8 b = *(const bf16x8*)(&sWT[n][lq * 8]);
      float cv = sC[n];
      #pragma unroll
      for (int t = 0; t < 2; t++) {
        f32x4 acc = {cv, cv, cv, cv};
        acc = __builtin_amdgcn_mfma_f32_16x16x32_bf16(a[t], b, acc, 0, 0, 0);
        bf16x4 mh = {(bf16)acc[0], (bf16)acc[1], (bf16)acc[2], (bf16)acc[3]};
        mixh[t][jj] = mh;
        #pragma unroll
        for (int r = 0; r < 4; r++) sAct[0][t * 16 + lq * 4 + r][n] = mh[r];
      }
    }
  }
  __syncthreads();

  // generic phase: A-tiles from sAct[src], B loaded fp32 -> cvt bf16 in regs
  auto gemmPhase = [&](int src, const float* __restrict__ W, auto&& epi) {
    bf16x8 af[2][8];
    #pragma unroll
    for (int t = 0; t < 2; t++)
      #pragma unroll
      for (int ks = 0; ks < 8; ks++)
        af[t][ks] = *(const bf16x8*)(&sAct[src][t * 16 + lm][ks * 32 + lq * 8]);
    // per lane: row = (j0+jj)*16+lm, cols ks*32 + lq*8 .. +7 (fp32, row-major)
    const float* base = W + (size_t)(j0 * 16 + lm) * D_ + lq * 8;
    bf16x8 bb[8];
    #pragma unroll
    for (int ks = 0; ks < 8; ks++) {
      float4 p0 = *(const float4*)(base + ks * 32);
      float4 p1 = *(const float4*)(base + ks * 32 + 4);
      bb[ks] = cvt8(p0, p1);
    }
    #pragma unroll
    for (int jj = 0; jj < 4; jj++) {
      float4 na[8], nb[8];
      if (jj < 3) {
        const float* nbp = base + (size_t)(jj + 1) * 16 * D_;
        #pragma unroll
        for (int ks = 0; ks < 8; ks++) {
          na[ks] = *(const float4*)(nbp + ks * 32);
          nb[ks] = *(const float4*)(nbp + ks * 32 + 4);
        }
      }
      f32x4 acc0 = {0.f, 0.f, 0.f, 0.f}, acc1 = {0.f, 0.f, 0.f, 0.f};
      #pragma unroll
      for (int ks = 0; ks < 8; ks++) {
        acc0 = __builtin_amdgcn_mfma_f32_16x16x32_bf16(af[0][ks], bb[ks], acc0, 0, 0, 0);
        acc1 = __builtin_amdgcn_mfma_f32_16x16x32_bf16(af[1][ks], bb[ks], acc1, 0, 0, 0);
      }
      epi(jj, acc0, acc1);
      if (jj < 3) {
        #pragma unroll
        for (int ks = 0; ks < 8; ks++) bb[ks] = cvt8(na[ks], nb[ks]);
      }
    }
  };

  // ---- phase 2: h1 = elu(mix @ fc1^T + b1) -> sAct[1] ----
  gemmPhase(0, FC1, [&](int jj, f32x4& a0, f32x4& a1) {
    int n = (j0 + jj) * 16 + lm;
    float bias = fc1_b[n];
    #pragma unroll
    for (int r = 0; r < 4; r++) {
      float v0 = a0[r] + bias;
      v0 = (v0 > 0.0f) ? v0 : (__expf(v0) - 1.0f);
      sAct[1][lq * 4 + r][n] = (bf16)v0;
      float v1 = a1[r] + bias;
      v1 = (v1 > 0.0f) ? v1 : (__expf(v1) - 1.0f);
      sAct[1][16 + lq * 4 + r][n] = (bf16)v1;
    }
  });
  __syncthreads();

  // ---- phase 3: h2 = h1 @ fc2^T + b2 -> sAct[0], keep packed regs ----
  bf16x4 h2h[2][4];
  gemmPhase(1, FC2, [&](int jj, f32x4& a0, f32x4& a1) {
    int n = (j0 + jj) * 16 + lm;
    float bias = fc2_b[n];
    bf16x4 h0, h1v;
    #pragma unroll
    for (int r = 0; r < 4; r++) {
      h0[r]  = (bf16)(a0[r] + bias);
      h1v[r] = (bf16)(a1[r] + bias);
      sAct[0][lq * 4 + r][n] = h0[r];
      sAct[0][16 + lq * 4 + r][n] = h1v[r];
    }
    h2h[0][jj] = h0;
    h2h[1][jj] = h1v;
  });
  __syncthreads();

  // ---- phase 4: gate, gated skip -> sY ----
  gemmPhase(0, GATE, [&](int jj, f32x4& a0, f32x4& a1) {
    int n = (j0 + jj) * 16 + lm;
    float bias = gate_b[n];
    #pragma unroll
    for (int r = 0; r < 4; r++) {
      float s0 = a0[r] + bias;
      float g0 = 1.0f / (1.0f + __expf(-s0));
      sY[lq * 4 + r][n] = g0 * (float)h2h[0][jj][r] + (1.0f - g0) * (float)mixh[0][jj][r];
      float s1 = a1[r] + bias;
      float g1 = 1.0f / (1.0f + __expf(-s1));
      sY[16 + lq * 4 + r][n] = g1 * (float)h2h[1][jj][r] + (1.0f - g1) * (float)mixh[1][jj][r];
    }
  });
  __syncthreads();

  // ---- phase 5: LayerNorm(256); 16-lane group handles 2 tokens ----
  const float inv_d = 1.0f / 256.0f;
  #pragma unroll
  for (int rep = 0; rep < 2; rep++) {
    const int t = (w * 4 + lq) * 2 + rep;
    float4 yv[4];
    #pragma unroll
    for (int i = 0; i < 4; i++)
      yv[i] = *(const float4*)(&sY[t][lm * 4 + i * 64]);
    float s = 0.0f;
    #pragma unroll
    for (int i = 0; i < 4; i++) s += yv[i].x + yv[i].y + yv[i].z + yv[i].w;
    #pragma unroll
    for (int off = 1; off < 16; off <<= 1) s += __shfl_xor(s, off);
    float mean = s * inv_d;
    float q = 0.0f;
    #pragma unroll
    for (int i = 0; i < 4; i++) {
      float d0 = yv[i].x - mean, d1 = yv[i].y - mean,
            d2 = yv[i].z - mean, d3 = yv[i].w - mean;
      q += d0 * d0 + d1 * d1 + d2 * d2 + d3 * d3;
    }
    #pragma unroll
    for (int off = 1; off < 16; off <<= 1) q += __shfl_xor(q, off);
    float rstd = rsqrtf(q * inv_d + 1e-5f);
    #pragma unroll
    for (int i = 0; i < 4; i++) {
      int n = lm * 4 + i * 64;
      float4 gv = *(const float4*)(ln_g + n);
      float4 bv = *(const float4*)(ln_b + n);
      float4 o;
      o.x = (yv[i].x - mean) * rstd * gv.x + bv.x;
      o.y = (yv[i].y - mean) * rstd * gv.y + bv.y;
      o.z = (yv[i].z - mean) * rstd * gv.z + bv.z;
      o.w = (yv[i].w - mean) * rstd * gv.w + bv.w;
      *(float4*)(out + (size_t)(tok0 + t) * D_ + n) = o;
    }
  }
}

extern "C" void kernel_launch(void* const* d_in, const int* in_sizes, int n_in,
                              void* d_out, int out_size, void* d_ws, size_t ws_size,
                              hipStream_t stream) {
  (void)in_sizes; (void)n_in; (void)ws_size; (void)out_size; (void)d_ws;
  const float* x      = (const float*)d_in[0];
  const float* proj_w = (const float*)d_in[1];
  const float* proj_b = (const float*)d_in[2];
  const float* sclnb  = (const float*)d_in[12];
  const float* fc1w   = (const float*)d_in[13];
  const float* fc1b   = (const float*)d_in[14];
  const float* fc2w   = (const float*)d_in[15];
  const float* fc2b   = (const float*)d_in[16];
  const float* gw     = (const float*)d_in[17];
  const float* gb     = (const float*)d_in[18];
  const float* lng    = (const float*)d_in[19];
  const float* lnb    = (const float*)d_in[20];

  vsn_fused<<<NTOK / 32, 256, 0, stream>>>(x, proj_w, proj_b, sclnb,
                                           fc1w, fc1b, fc2w, fc2b, gw, gb,
                                           lng, lnb, (float*)d_out);
}